// Round 8
// baseline (162.234 us; speedup 1.0000x reference)
//
#include <hip/hip_runtime.h>

#define N_ROWS 131072
#define DIM 64
#define KCODES 512
#define MARGIN 1e-4f

typedef __attribute__((ext_vector_type(8))) short bf16x8;
typedef __attribute__((ext_vector_type(4))) float f32x4;

// ws layout (4-byte words):
// [0..512)        bnp f32[512]
// [512..33280)    wfrag ushort[65536]  B-fragment image:
//                 frag = cti*256 + q*64 + lane (16B units); q: 0=hi k0,1=hi k1,2=lo k0,3=lo k1
// [33280..35328)  hist4 u32[4][512]  striped count partials
// [35328..35584)  lossp f32[256]     per-block loss partials

__device__ __forceinline__ float sqr_nf(float x) {
    float s = x * x;
    asm("" : "+v"(s));   // numpy rounds the square before summing
    return s;
}

__device__ __forceinline__ unsigned short f2bf(float f) {  // RNE, finite data
    unsigned u = __float_as_uint(f);
    u += 0x7fffu + ((u >> 16) & 1u);
    return (unsigned short)(u >> 16);
}
__device__ __forceinline__ float bf2f(unsigned short b) {
    return __uint_as_float(((unsigned)b) << 16);
}

__device__ __forceinline__ void cvtpair(float4 a, float4 b, bf16x8& hi, bf16x8& lo) {
    float v[8] = {a.x, a.y, a.z, a.w, b.x, b.y, b.z, b.w};
#pragma unroll
    for (int j = 0; j < 8; ++j) {
        unsigned short h = f2bf(v[j]);
        hi[j] = (short)h;
        lo[j] = (short)f2bf(v[j] - bf2f(h));
    }
}
__device__ __forceinline__ float4 scl(float4 v, float s) {
    return make_float4(v.x * s, v.y * s, v.z * s, v.w * s);
}

// ---- precompute: W -> bf16 hi/lo B-fragment image + np-exact norms ---------
__global__ __launch_bounds__(256) void vq_wprep_k(
    const float* __restrict__ W, unsigned short* __restrict__ wfrag,
    float* __restrict__ bnp) {
    int code = blockIdx.x * 256 + threadIdx.x;   // 0..511
    float p[64];
#pragma unroll
    for (int i = 0; i < 16; ++i) {
        float4 v = reinterpret_cast<const float4*>(W)[code * 16 + i];
        p[i * 4 + 0] = v.x; p[i * 4 + 1] = v.y;
        p[i * 4 + 2] = v.z; p[i * 4 + 3] = v.w;
    }
    unsigned short hi[64], lo[64];
#pragma unroll
    for (int d = 0; d < 64; ++d) {
        hi[d] = f2bf(p[d]);
        lo[d] = f2bf(p[d] - bf2f(hi[d]));
    }
    {   // np pairwise codeword norm  [validated rounds 3-7, absmax 0]
        float r[8];
#pragma unroll
        for (int j = 0; j < 8; ++j) r[j] = sqr_nf(p[j]);
#pragma unroll
        for (int i = 1; i < 8; ++i)
#pragma unroll
            for (int j = 0; j < 8; ++j) r[j] += sqr_nf(p[i * 8 + j]);
        bnp[code] = ((r[0] + r[1]) + (r[2] + r[3])) + ((r[4] + r[5]) + (r[6] + r[7]));
    }
    const int cti = code >> 4, m = code & 15;
#pragma unroll
    for (int part = 0; part < 2; ++part) {
        const unsigned short* src = part ? lo : hi;
#pragma unroll
        for (int s = 0; s < 2; ++s) {
            int q = part * 2 + s;
#pragma unroll
            for (int kq = 0; kq < 4; ++kq) {
                int lane = kq * 16 + m;
                size_t off = ((size_t)(cti * 4 + q) * 64 + lane) * 8;
                *reinterpret_cast<uint4*>(wfrag + off) =
                    *reinterpret_cast<const uint4*>(src + s * 32 + kq * 8);
            }
        }
    }
}

// ---- fused main: 256 blocks x 1024 thr, full B image in LDS, no global atomics
__global__ __launch_bounds__(1024) void vq_fused_k(
    const float* __restrict__ X, const float* __restrict__ Wf,
    const unsigned short* __restrict__ wfrag, const float* __restrict__ bnp,
    float* __restrict__ out_q, float* __restrict__ out_idx,
    unsigned* __restrict__ hist4, float* __restrict__ lossp) {
    __shared__ __align__(16) unsigned short Wlds[65536];  // 128 KB
    __shared__ float bnp_s[KCODES];
    __shared__ int idx_s[512];
    __shared__ unsigned hist[KCODES];
    __shared__ float lred[16];

    const int tid = threadIdx.x;
    const int lane = tid & 63, w = tid >> 6;   // 16 waves
    const int m = lane & 15, kq = lane >> 4;
    const long rbase = (long)blockIdx.x * 512;

    // stage: B image (128KB), bnp, zero hist
    {
        const uint4* g = reinterpret_cast<const uint4*>(wfrag);
        uint4* l4 = reinterpret_cast<uint4*>(Wlds);
#pragma unroll
        for (int i = 0; i < 8; ++i) l4[i * 1024 + tid] = g[i * 1024 + tid];
    }
    if (tid < KCODES) { bnp_s[tid] = bnp[tid]; hist[tid] = 0; }

    // A-fragments hold -2x (exact scale): lane (m,kq) holds A[m][kq*8+j]
    bf16x8 ahi[2][2], alo[2][2];
#pragma unroll
    for (int rt = 0; rt < 2; ++rt) {
        long row = rbase + w * 32 + rt * 16 + m;
        const float4* xp = reinterpret_cast<const float4*>(X + row * DIM);
        cvtpair(scl(xp[kq * 2], -2.f), scl(xp[kq * 2 + 1], -2.f),
                ahi[rt][0], alo[rt][0]);
        cvtpair(scl(xp[8 + kq * 2], -2.f), scl(xp[8 + kq * 2 + 1], -2.f),
                ahi[rt][1], alo[rt][1]);
    }
    __syncthreads();   // Wlds + bnp_s + hist ready

    float best[2][4], sec[2][4];
    int bidx[2][4];
#pragma unroll
    for (int rt = 0; rt < 2; ++rt)
#pragma unroll
        for (int j = 0; j < 4; ++j) { best[rt][j] = 3e38f; sec[rt][j] = 3e38f; bidx[rt][j] = 0; }

    const bf16x8* fp = reinterpret_cast<const bf16x8*>(Wlds);
    for (int cti = 0; cti < 32; ++cti) {
        bf16x8 b0 = fp[(cti * 4 + 0) * 64 + lane];
        bf16x8 b1 = fp[(cti * 4 + 1) * 64 + lane];
        bf16x8 b2 = fp[(cti * 4 + 2) * 64 + lane];
        bf16x8 b3 = fp[(cti * 4 + 3) * 64 + lane];
        const int kk = cti * 16 + m;
        const float wn = bnp_s[kk];
        // score = wn + sum((-2x) * w)  -- C-init carries wn, chain accumulates
        f32x4 c0 = {wn, wn, wn, wn};
        f32x4 c1 = {wn, wn, wn, wn};
        c0 = __builtin_amdgcn_mfma_f32_16x16x32_bf16(ahi[0][0], b0, c0, 0, 0, 0);
        c1 = __builtin_amdgcn_mfma_f32_16x16x32_bf16(ahi[1][0], b0, c1, 0, 0, 0);
        c0 = __builtin_amdgcn_mfma_f32_16x16x32_bf16(ahi[0][1], b1, c0, 0, 0, 0);
        c1 = __builtin_amdgcn_mfma_f32_16x16x32_bf16(ahi[1][1], b1, c1, 0, 0, 0);
        c0 = __builtin_amdgcn_mfma_f32_16x16x32_bf16(alo[0][0], b0, c0, 0, 0, 0);
        c1 = __builtin_amdgcn_mfma_f32_16x16x32_bf16(alo[1][0], b0, c1, 0, 0, 0);
        c0 = __builtin_amdgcn_mfma_f32_16x16x32_bf16(alo[0][1], b1, c0, 0, 0, 0);
        c1 = __builtin_amdgcn_mfma_f32_16x16x32_bf16(alo[1][1], b1, c1, 0, 0, 0);
        c0 = __builtin_amdgcn_mfma_f32_16x16x32_bf16(ahi[0][0], b2, c0, 0, 0, 0);
        c1 = __builtin_amdgcn_mfma_f32_16x16x32_bf16(ahi[1][0], b2, c1, 0, 0, 0);
        c0 = __builtin_amdgcn_mfma_f32_16x16x32_bf16(ahi[0][1], b3, c0, 0, 0, 0);
        c1 = __builtin_amdgcn_mfma_f32_16x16x32_bf16(ahi[1][1], b3, c1, 0, 0, 0);
#pragma unroll
        for (int j = 0; j < 4; ++j) {
            float s0 = c0[j], s1 = c1[j];
            if (s0 < best[0][j]) { sec[0][j] = best[0][j]; best[0][j] = s0; bidx[0][j] = kk; }
            else if (s0 < sec[0][j]) sec[0][j] = s0;
            if (s1 < best[1][j]) { sec[1][j] = best[1][j]; best[1][j] = s1; bidx[1][j] = kk; }
            else if (s1 < sec[1][j]) sec[1][j] = s1;
        }
    }

    // merge across the 16 m-lanes; exact ties -> smaller index
#pragma unroll
    for (int st = 1; st < 16; st <<= 1) {
#pragma unroll
        for (int rt = 0; rt < 2; ++rt)
#pragma unroll
            for (int j = 0; j < 4; ++j) {
                float ob = __shfl_xor(best[rt][j], st);
                float os = __shfl_xor(sec[rt][j], st);
                int oi = __shfl_xor(bidx[rt][j], st);
                if (ob < best[rt][j] || (ob == best[rt][j] && oi < bidx[rt][j])) {
                    sec[rt][j] = fminf(best[rt][j], os);
                    best[rt][j] = ob; bidx[rt][j] = oi;
                } else {
                    sec[rt][j] = fminf(sec[rt][j], ob);
                }
            }
    }

    if (m == 0) {   // C/D row = kq*4 + j
#pragma unroll
        for (int rt = 0; rt < 2; ++rt)
#pragma unroll
            for (int j = 0; j < 4; ++j) {
                int r = w * 32 + rt * 16 + kq * 4 + j;
                int id = (sec[rt][j] - best[rt][j] <= MARGIN) ? -1 : bidx[rt][j];
                idx_s[r] = id;
                out_idx[rbase + r] = (float)id;   // sentinel overwritten by refine
            }
    }
    __syncthreads();

    // block-wide epilogue: quantized_st + loss (skip flagged rows)
    float ls = 0.f;
#pragma unroll
    for (int i = 0; i < 8; ++i) {
        int f = i * 4096 + tid * 4;
        int r = f >> 6, d = f & 63;
        int k = idx_s[r];
        if (k >= 0) {
            float4 x = *reinterpret_cast<const float4*>(&X[(rbase + r) * DIM + d]);
            float4 q = *reinterpret_cast<const float4*>(&Wf[k * DIM + d]);
            float4 o;
            float t;
            t = q.x - x.x; o.x = x.x + t; ls = fmaf(t, t, ls);
            t = q.y - x.y; o.y = x.y + t; ls = fmaf(t, t, ls);
            t = q.z - x.z; o.z = x.z + t; ls = fmaf(t, t, ls);
            t = q.w - x.w; o.w = x.w + t; ls = fmaf(t, t, ls);
            *reinterpret_cast<float4*>(&out_q[(rbase + r) * DIM + d]) = o;
        }
    }

    // counts into LDS histogram (this wave's 32 rows)
    if (lane < 32) {
        int k = idx_s[w * 32 + lane];
        if (k >= 0) atomicAdd(&hist[k], 1u);
    }

    // inline np-bit-exact resolve of this wave's flagged rows [validated r6/r7]
    for (int r = 0; r < 32; ++r) {
        if (idx_s[w * 32 + r] >= 0) continue;      // wave-uniform branch
        const long row = rbase + w * 32 + r;
        const float xv = X[row * DIM + lane];      // lane d holds x[d]
        float sq = sqr_nf(xv);
        float rr = sq;
#pragma unroll
        for (int i = 1; i < 8; ++i) rr += __shfl(sq, (lane & 7) + 8 * i);
        float t01 = rr + __shfl_xor(rr, 1);
        float t03 = t01 + __shfl_xor(t01, 2);
        float Afull = t03 + __shfl_xor(t03, 4);
        const float A = __shfl(Afull, 0);
        float acc[8];
#pragma unroll
        for (int c = 0; c < 8; ++c) acc[c] = 0.f;
        for (int d0 = 0; d0 < 16; ++d0) {
            float x0 = __shfl(xv, d0 * 4 + 0);
            float x1 = __shfl(xv, d0 * 4 + 1);
            float x2 = __shfl(xv, d0 * 4 + 2);
            float x3 = __shfl(xv, d0 * 4 + 3);
#pragma unroll
            for (int c = 0; c < 8; ++c) {
                float4 wq = *reinterpret_cast<const float4*>(
                    &Wf[(lane * 8 + c) * DIM + d0 * 4]);
                acc[c] = fmaf(x0, wq.x, acc[c]);
                acc[c] = fmaf(x1, wq.y, acc[c]);
                acc[c] = fmaf(x2, wq.z, acc[c]);
                acc[c] = fmaf(x3, wq.w, acc[c]);
            }
        }
        float bs = 3e38f;
        int bi = 0;
#pragma unroll
        for (int c = 0; c < 8; ++c) {
            int k = lane * 8 + c;
            float u = A + bnp_s[k];
            float s = u - 2.0f * acc[c];
            if (s < bs) { bs = s; bi = k; }   // ascending k, strict <
        }
#pragma unroll
        for (int st = 1; st < 64; st <<= 1) {
            float ob = __shfl_xor(bs, st);
            int oi = __shfl_xor(bi, st);
            if (ob < bs || (ob == bs && oi < bi)) { bs = ob; bi = oi; }
        }
        const int k = bi;
        if (lane == 0) { out_idx[row] = (float)k; atomicAdd(&hist[k], 1u); }
        float qv = Wf[k * DIM + lane];
        float diff = qv - xv;
        out_q[row * DIM + lane] = xv + diff;
        ls = fmaf(diff, diff, ls);
    }

#pragma unroll
    for (int st = 1; st < 64; st <<= 1) ls += __shfl_xor(ls, st);
    if (lane == 0) lred[w] = ls;
    __syncthreads();   // hist complete, lred complete

    // flush: nonzero counters to striped partials (no hot-spot atomics)
    if (tid < KCODES) {
        unsigned v = hist[tid];
        if (v) atomicAdd(&hist4[(blockIdx.x & 3) * KCODES + tid], v);
    }
    if (tid == 0) {
        float s = 0.f;
#pragma unroll
        for (int i = 0; i < 16; ++i) s += lred[i];
        lossp[blockIdx.x] = s;
    }
}

__global__ __launch_bounds__(512) void vq_finalize_k(
    const unsigned* __restrict__ hist4, const float* __restrict__ lossp,
    float* __restrict__ out_loss, float* __restrict__ out_perp) {
    __shared__ float red[512];
    int t = threadIdx.x;
    unsigned c = hist4[t] + hist4[512 + t] + hist4[1024 + t] + hist4[1536 + t];
    float p = (float)c * (1.0f / (float)N_ROWS);
    red[t] = p * logf(p + 1e-10f);
    __syncthreads();
    for (int off = 256; off; off >>= 1) {
        if (t < off) red[t] += red[t + off];
        __syncthreads();
    }
    if (t == 0) *out_perp = expf(-red[0]);
    __syncthreads();
    red[t] = (t < 256) ? lossp[t] : 0.f;
    __syncthreads();
    for (int off = 256; off; off >>= 1) {
        if (t < off) red[t] += red[t + off];
        __syncthreads();
    }
    if (t == 0) {
        float m = red[0] / (float)(N_ROWS * DIM);
        *out_loss = m + 0.25f * m;
    }
}

extern "C" void kernel_launch(void* const* d_in, const int* in_sizes, int n_in,
                              void* d_out, int out_size, void* d_ws, size_t ws_size,
                              hipStream_t stream) {
    const float* X = (const float*)d_in[0];
    const float* Wf = (const float*)d_in[1];

    float* out = (float*)d_out;
    float* out_loss = out;
    float* out_q = out + 1;
    float* out_perp = out + 1 + (long)N_ROWS * DIM;
    float* out_idx = out + 2 + (long)N_ROWS * DIM;

    unsigned* wsu = (unsigned*)d_ws;
    float* bnp = (float*)wsu;                       // [0..512)
    unsigned short* wfrag = (unsigned short*)(wsu + 512);   // [512..33280)
    unsigned* hist4 = wsu + 33280;                  // [33280..35328)
    float* lossp = (float*)(wsu + 35328);           // [35328..35584)

    hipMemsetAsync(hist4, 0, 4 * KCODES * sizeof(unsigned), stream);
    vq_wprep_k<<<2, 256, 0, stream>>>(Wf, wfrag, bnp);
    vq_fused_k<<<N_ROWS / 512, 1024, 0, stream>>>(X, Wf, wfrag, bnp,
                                                  out_q, out_idx, hist4, lossp);
    vq_finalize_k<<<1, 512, 0, stream>>>(hist4, lossp, out_loss, out_perp);
}